// Round 13
// baseline (321.300 us; speedup 1.0000x reference)
//
#include <hip/hip_runtime.h>
#include <math.h>

typedef _Float16 h16;
typedef __attribute__((ext_vector_type(4))) _Float16 half4;
typedef __attribute__((ext_vector_type(8))) _Float16 half8;
typedef __attribute__((ext_vector_type(4))) float f32x4;

#define AS1 __attribute__((address_space(1)))
#define AS3 __attribute__((address_space(3)))
#define MFMA16(a, b, c) __builtin_amdgcn_mfma_f32_16x16x32_f16((a), (b), (c), 0, 0, 0)

__device__ __forceinline__ float ex2(float x) {
  return __builtin_amdgcn_exp2f(x);
}

// DPP lane ops (VALU pipe, not LDS pipe). Reduce within each 16-lane row.
template <int CTRL>
__device__ __forceinline__ float dppf(float x) {
  return __int_as_float(__builtin_amdgcn_update_dpp(
      0, __float_as_int(x), CTRL, 0xF, 0xF, true));
}
__device__ __forceinline__ float rmax16(float x) {
  x = fmaxf(x, dppf<0xB1>(x));   // quad_perm xor1
  x = fmaxf(x, dppf<0x4E>(x));   // quad_perm xor2
  x = fmaxf(x, dppf<0x124>(x));  // row_ror:4
  x = fmaxf(x, dppf<0x128>(x));  // row_ror:8
  return x;
}
__device__ __forceinline__ float rsum16(float x) {
  x += dppf<0xB1>(x);
  x += dppf<0x4E>(x);
  x += dppf<0x124>(x);
  x += dppf<0x128>(x);
  return x;
}

// ---------- convert: fp32 -> fp16 for q/k/v, Wq/Wk/Wv/Wo, rel ----------
__global__ __launch_bounds__(256) void convert(
    const float* __restrict__ q, const float* __restrict__ k,
    const float* __restrict__ v, const float* __restrict__ Wq,
    const float* __restrict__ Wk, const float* __restrict__ Wv,
    const float* __restrict__ Wo, const float* __restrict__ rel, h16* q16c,
    h16* k16c, h16* v16c, h16* Wq16, h16* Wk16, h16* Wv16, h16* Wo16,
    h16* relb) {
  const int i = blockIdx.x * 256 + threadIdx.x;  // float4 units
  if (i >= 4226304) return;
  const float* src;
  h16* dst;
  int off;
  if (i < 1048576) {
    src = q; dst = q16c; off = i;
  } else if (i < 2097152) {
    src = k; dst = k16c; off = i - 1048576;
  } else if (i < 3145728) {
    src = v; dst = v16c; off = i - 2097152;
  } else if (i < 3407872) {
    src = Wq; dst = Wq16; off = i - 3145728;
  } else if (i < 3670016) {
    src = Wk; dst = Wk16; off = i - 3407872;
  } else if (i < 3932160) {
    src = Wv; dst = Wv16; off = i - 3670016;
  } else if (i < 4194304) {
    src = Wo; dst = Wo16; off = i - 3932160;
  } else {
    off = i - 4194304;  // rel: 32000 f4 units; src valid below 31984
    half4 hv = (half4){(h16)0.f, (h16)0.f, (h16)0.f, (h16)0.f};
    if (off < 31984) {
      float4 f = *(const float4*)(rel + (size_t)off * 4);
      hv = (half4){(h16)f.x, (h16)f.y, (h16)f.z, (h16)f.w};
    }
    *(half4*)(relb + (size_t)off * 4) = hv;
    return;
  }
  float4 f = *(const float4*)(src + (size_t)off * 4);
  *(half4*)(dst + (size_t)off * 4) =
      (half4){(h16)f.x, (h16)f.y, (h16)f.z, (h16)f.w};
}

// ---------- 128x128 fp16 NT GEMM, BK=64, XOR-swizzled LDS (R9) ----------
// C[m,n] = sum_k A[m,k]*Bt[n,k] + bias[n]. M=4096,N=1024,K=1024.
// 2-phase; best-measured structure for this problem shape (R11's 8-phase
// 256x256 regressed: depth-1 vmcnt(0) pipeline + 75% CU coverage).
// MODE 0: h16 out scattered [B,H,T,64]; MODE 1: h16 out [B,H,64,T].
template <int MODE>
__device__ __forceinline__ void gemm128_body(const h16* __restrict__ A,
                                             const h16* __restrict__ Bt,
                                             const float* __restrict__ bias,
                                             h16* __restrict__ outp) {
  __shared__ alignas(16) h16 As[128 * 64];  // 16 KB swizzled
  __shared__ alignas(16) h16 Bs[128 * 64];  // 16 KB swizzled
  const int tid = threadIdx.x;
  const int wave = tid >> 6;
  const int lane = tid & 63;
  const int wm = wave >> 1, wn = wave & 1;
  const int tm0 = blockIdx.x * 128, tn0 = blockIdx.y * 128;
  const int lrow = lane & 15;
  const int kq = lane >> 4;

  f32x4 acc[4][4];
#pragma unroll
  for (int i = 0; i < 4; ++i)
#pragma unroll
    for (int j = 0; j < 4; ++j) acc[i][j] = (f32x4){0.f, 0.f, 0.f, 0.f};

  for (int k0 = 0; k0 < 1024; k0 += 64) {
    __syncthreads();
#pragma unroll
    for (int p = 0; p < 4; ++p) {
      const int a = (wave * 4 + p) * 64 + lane;
      const int row = a >> 3;
      const int c = (a & 7) ^ (row & 7);
      __builtin_amdgcn_global_load_lds(
          (const AS1 void*)(A + (size_t)(tm0 + row) * 1024 + k0 + c * 8),
          (AS3 void*)(As + (wave * 4 + p) * 512), 16, 0, 0);
      __builtin_amdgcn_global_load_lds(
          (const AS1 void*)(Bt + (size_t)(tn0 + row) * 1024 + k0 + c * 8),
          (AS3 void*)(Bs + (wave * 4 + p) * 512), 16, 0, 0);
    }
    __syncthreads();
    // all fragment rows are (multiple of 16) + lrow -> row&7 == lrow&7
#pragma unroll
    for (int ks2 = 0; ks2 < 2; ++ks2) {
      const int cu = ((ks2 * 4 + kq) ^ (lrow & 7)) << 3;  // h16 offset
      half8 af[4], bf[4];
#pragma unroll
      for (int i = 0; i < 4; ++i)
        af[i] = *(const half8*)(As + (wm * 64 + i * 16 + lrow) * 64 + cu);
#pragma unroll
      for (int j = 0; j < 4; ++j)
        bf[j] = *(const half8*)(Bs + (wn * 64 + j * 16 + lrow) * 64 + cu);
#pragma unroll
      for (int i = 0; i < 4; ++i)
#pragma unroll
        for (int j = 0; j < 4; ++j)
          acc[i][j] = MFMA16(af[i], bf[j], acc[i][j]);
    }
  }

#pragma unroll
  for (int j = 0; j < 4; ++j) {
    const int n = tn0 + wn * 64 + j * 16 + lrow;
    const float bval = bias[n];
#pragma unroll
    for (int i = 0; i < 4; ++i) {
      const int rowb = wm * 64 + i * 16 + kq * 4;
#pragma unroll
      for (int r = 0; r < 4; ++r) {
        const int m = tm0 + rowb + r;
        const float val = acc[i][j][r] + bval;
        const int b = m >> 10, t = m & 1023, hh = n >> 6, d = n & 63;
        if (MODE == 0) {
          outp[((size_t)((b << 4) + hh) << 16) + (t << 6) + d] = (h16)val;
        } else {
          outp[(((size_t)((b << 4) + hh) * 64 + d) << 10) + t] = (h16)val;
        }
      }
    }
  }
}

__global__ __launch_bounds__(256) void qkv_gemm(
    const h16* q16c, const h16* k16c, const h16* v16c, const h16* Wq16,
    const h16* Wk16, const h16* Wv16, const float* bq, const float* bk,
    const float* bv, h16* q16, h16* k16, h16* vt16) {
  const int z = blockIdx.z;
  const h16* A = (z == 0) ? q16c : (z == 1) ? k16c : v16c;
  const h16* Bt = (z == 0) ? Wq16 : (z == 1) ? Wk16 : Wv16;
  const float* bias = (z == 0) ? bq : (z == 1) ? bk : bv;
  if (z == 2)
    gemm128_body<1>(A, Bt, bias, vt16);
  else
    gemm128_body<0>(A, Bt, bias, (z == 0) ? q16 : k16);
}

// ---------- out GEMM: 64x128 tile, BK=64, swizzled (512 blocks) ----------
__global__ __launch_bounds__(256) void out_gemm(const h16* __restrict__ A,
                                                const h16* __restrict__ Bt,
                                                const float* __restrict__ bo,
                                                float* __restrict__ out) {
  __shared__ alignas(16) h16 As[64 * 64];   // 8 KB swizzled
  __shared__ alignas(16) h16 Bs[128 * 64];  // 16 KB swizzled
  const int tid = threadIdx.x;
  const int wave = tid >> 6;
  const int lane = tid & 63;
  const int wm = wave >> 1, wn = wave & 1;
  const int tm0 = blockIdx.x * 64, tn0 = blockIdx.y * 128;
  const int lrow = lane & 15;
  const int kq = lane >> 4;

  f32x4 acc[2][4];
#pragma unroll
  for (int i = 0; i < 2; ++i)
#pragma unroll
    for (int j = 0; j < 4; ++j) acc[i][j] = (f32x4){0.f, 0.f, 0.f, 0.f};

  for (int k0 = 0; k0 < 1024; k0 += 64) {
    __syncthreads();
#pragma unroll
    for (int p = 0; p < 2; ++p) {  // A tile: 512 units, 2/thread
      const int a = (wave * 2 + p) * 64 + lane;
      const int row = a >> 3;  // 0..63
      const int c = (a & 7) ^ (row & 7);
      __builtin_amdgcn_global_load_lds(
          (const AS1 void*)(A + (size_t)(tm0 + row) * 1024 + k0 + c * 8),
          (AS3 void*)(As + (wave * 2 + p) * 512), 16, 0, 0);
    }
#pragma unroll
    for (int p = 0; p < 4; ++p) {  // B tile: 1024 units, 4/thread
      const int a = (wave * 4 + p) * 64 + lane;
      const int row = a >> 3;  // 0..127
      const int c = (a & 7) ^ (row & 7);
      __builtin_amdgcn_global_load_lds(
          (const AS1 void*)(Bt + (size_t)(tn0 + row) * 1024 + k0 + c * 8),
          (AS3 void*)(Bs + (wave * 4 + p) * 512), 16, 0, 0);
    }
    __syncthreads();
#pragma unroll
    for (int ks2 = 0; ks2 < 2; ++ks2) {
      const int cu = ((ks2 * 4 + kq) ^ (lrow & 7)) << 3;
      half8 af[2], bf[4];
#pragma unroll
      for (int i = 0; i < 2; ++i)
        af[i] = *(const half8*)(As + (wm * 32 + i * 16 + lrow) * 64 + cu);
#pragma unroll
      for (int j = 0; j < 4; ++j)
        bf[j] = *(const half8*)(Bs + (wn * 64 + j * 16 + lrow) * 64 + cu);
#pragma unroll
      for (int i = 0; i < 2; ++i)
#pragma unroll
        for (int j = 0; j < 4; ++j)
          acc[i][j] = MFMA16(af[i], bf[j], acc[i][j]);
    }
  }

#pragma unroll
  for (int j = 0; j < 4; ++j) {
    const int n = tn0 + wn * 64 + j * 16 + lrow;
    const float bval = bo[n];
#pragma unroll
    for (int i = 0; i < 2; ++i) {
      const int rowb = wm * 32 + i * 16 + kq * 4;
#pragma unroll
      for (int r = 0; r < 4; ++r) {
        const int m = tm0 + rowb + r;
        out[(size_t)m * 1024 + n] = acc[i][j][r] + bval;
      }
    }
  }
}

// ---------- MFMA fused attention (fp16) ----------
// R13 = exact R9 structure (full 16 KB Rl staging — R12's ring reverted)
// + ONLY T13 defer-max: skip the O/ls rescale when mx - m2 <= 11.5
// (exp2-domain THR=8). P <= 2^11.5 fits fp16 Ps; condition uniform per
// 16-lane row group. First tile always rescales (m2 = -1e30).
// Diagnostic A/B: if R12's doubled FETCH/WRITE reproduce here, T13 is the
// toxin; if counters match R9 (~78.9 MB / 16384 KB), the ring was.
__global__ __launch_bounds__(256, 4) void attn_mfma(
    const h16* __restrict__ q16, const h16* __restrict__ k16,
    const h16* __restrict__ vt16, const h16* __restrict__ q16c,
    const h16* __restrict__ relb, h16* __restrict__ ao) {
  __shared__ alignas(16) h16 Kh[4096];   // 8 KB [64][64] swizzled
  __shared__ alignas(16) h16 Rl[8192];   // 16 KB [128][64] swizzled
  __shared__ alignas(16) h16 VtS[4096];  // 8 KB [64][64] swizzled
  __shared__ alignas(16) h16 Ps[4096];   // 8 KB [64][64] swizzled

  const int bid = blockIdx.x;
  const int ttile = bid & 15;
  const int bh = bid >> 4;
  const int b = bh >> 4, h = bh & 15;
  const int t0 = ttile << 6;
  const int tid = threadIdx.x;
  const int w = tid >> 6;
  const int lane = tid & 63;
  const int l15 = lane & 15;
  const int kq = lane >> 4;

  // Q fragment (projected) + raw-Q fragment, fp16, reused across s-tiles
  const int tq = t0 + w * 16 + l15;
  half8 aq[2], arq[2];
#pragma unroll
  for (int ks = 0; ks < 2; ++ks) {
    aq[ks] =
        *(const half8*)(q16 + ((size_t)bh * 1024 + tq) * 64 + kq * 8 + ks * 32);
    arq[ks] = *(const half8*)(q16c + ((size_t)(b * 1024 + tq)) * 1024 + h * 64 +
                              kq * 8 + ks * 32);
  }

  float m2[4], ls[4];
  f32x4 O[4];
#pragma unroll
  for (int r = 0; r < 4; ++r) {
    m2[r] = -1e30f;
    ls[r] = 0.f;
  }
#pragma unroll
  for (int db = 0; db < 4; ++db) O[db] = (f32x4){0.f, 0.f, 0.f, 0.f};

  const int trow = w * 16 + kq * 4;  // lane's block-local t base

  for (int s0 = 0; s0 < 1024; s0 += 64) {
    __syncthreads();  // all waves done reading Kh/Rl/VtS from prev iter

    // ---- staging: linear LDS dest, inverse-swizzled global source ----
    // unit a (16B) -> row = a>>3, cperm = a&7; source col c = cperm^(row&7)
#pragma unroll
    for (int p = 0; p < 2; ++p) {  // Kh: 8 KB = 8 wave-chunks, 2/wave
      const int a = (w * 2 + p) * 64 + lane;
      const int row = a >> 3;
      const int c = (a & 7) ^ (row & 7);
      __builtin_amdgcn_global_load_lds(
          (const AS1 void*)(k16 + ((size_t)(bh * 1024 + s0 + row)) * 64 +
                            c * 8),
          (AS3 void*)(Kh + (w * 2 + p) * 512), 16, 0, 0);
    }
#pragma unroll
    for (int p = 0; p < 2; ++p) {  // VtS: 8 KB, rows are d
      const int a = (w * 2 + p) * 64 + lane;
      const int row = a >> 3;
      const int c = (a & 7) ^ (row & 7);
      __builtin_amdgcn_global_load_lds(
          (const AS1 void*)(vt16 + ((size_t)(bh * 64 + row)) * 1024 + s0 +
                            c * 8),
          (AS3 void*)(VtS + (w * 2 + p) * 512), 16, 0, 0);
    }
    const int base = s0 - t0 + 999 - 63;
#pragma unroll
    for (int p = 0; p < 4; ++p) {  // Rl: 16 KB = 16 wave-chunks, 4/wave
      const int a = (w * 4 + p) * 64 + lane;
      const int row = a >> 3;
      const int c = (a & 7) ^ (row & 7);
      int ridx = base + row;
      ridx = ridx < 0 ? 0 : (ridx > 1998 ? 1998 : ridx);
      __builtin_amdgcn_global_load_lds(
          (const AS1 void*)(relb + (size_t)ridx * 64 + c * 8),
          (AS3 void*)(Rl + (w * 4 + p) * 512), 16, 0, 0);
    }
    __syncthreads();  // implicit vmcnt(0) drain -> LDS tiles ready

    // ---- QK^T strips ----
    __builtin_amdgcn_s_setprio(1);
    f32x4 S[4];
#pragma unroll
    for (int ns = 0; ns < 4; ++ns) {
      f32x4 s = (f32x4){0.f, 0.f, 0.f, 0.f};
      const int kr = ns * 16 + l15;
#pragma unroll
      for (int ks = 0; ks < 2; ++ks) {
        const int c = ((ks * 4 + kq) ^ (kr & 7)) << 3;
        s = MFMA16(aq[ks], *(const half8*)(Kh + kr * 64 + c), s);
      }
      S[ns] = s;
    }

    // ---- G[t][u] = rq . rel[u]; wave's u-window [(3-w)*16, (8-w)*16) ----
    f32x4 G[5];
#pragma unroll
    for (int gi = 0; gi < 5; ++gi) {
      f32x4 g = (f32x4){0.f, 0.f, 0.f, 0.f};
      const int ur = (3 - w + gi) * 16 + l15;
#pragma unroll
      for (int ks = 0; ks < 2; ++ks) {
        const int c = ((ks * 4 + kq) ^ (ur & 7)) << 3;
        g = MFMA16(arq[ks], *(const half8*)(Rl + ur * 64 + c), g);
      }
      G[gi] = g;
    }
    __builtin_amdgcn_s_setprio(0);

    // ---- in-register Toeplitz gather + logit scale ----
    // C = C0 + ns*16 - r = 16*(3+ns-w) + (15-kq*4-r); Cm = 15-kq*4-r is
    // ns-independent -> 1 bpermute per (ns,r) with merged select.
    const float SC = 11.54156032711170727f;  // 8 * log2(e)
#pragma unroll
    for (int r = 0; r < 4; ++r) {
      const int Cm = 15 - kq * 4 - r;
      const int sladdr = ((kq << 4) | ((l15 + Cm) & 15)) << 2;
      const bool nolap = (l15 >= Cm);
#pragma unroll
      for (int ns = 0; ns < 4; ++ns) {
        const float mv = nolap ? G[ns][r] : G[ns + 1][r];
        const float g = __int_as_float(
            __builtin_amdgcn_ds_bpermute(sladdr, __float_as_int(mv)));
        S[ns][r] = (S[ns][r] + g) * SC;
      }
    }

    // ---- online softmax (exp2 domain, DPP reduces, T13 defer-max) ----
#pragma unroll
    for (int r = 0; r < 4; ++r) {
      float mx = fmaxf(fmaxf(S[0][r], S[1][r]), fmaxf(S[2][r], S[3][r]));
      mx = rmax16(mx);
      if (mx - m2[r] > 11.5f) {  // rescale only on significant max growth
        const float al = ex2(m2[r] - mx);
        m2[r] = mx;
        ls[r] *= al;
        O[0][r] *= al;
        O[1][r] *= al;
        O[2][r] *= al;
        O[3][r] *= al;
      }
      const float nm = m2[r];
      const int t = trow + r;
      float rs = 0.f;
#pragma unroll
      for (int ns = 0; ns < 4; ++ns) {
        const float p = ex2(S[ns][r] - nm);  // bounded by 2^11.5, fits fp16
        rs += p;
        const int sl = ns * 16 + l15;
        Ps[t * 64 + (((sl >> 3) ^ (t & 7)) << 3) + (sl & 7)] = (h16)p;
      }
      rs = rsum16(rs);
      ls[r] += rs;
    }

    // ---- PV: O += P.V (A = own-wave P rows, B = VtS rows) ----
    const int tp = w * 16 + l15;
    __builtin_amdgcn_s_setprio(1);
#pragma unroll
    for (int ks = 0; ks < 2; ++ks) {
      const int ca = ((ks * 4 + kq) ^ (tp & 7)) << 3;
      half8 pa = *(const half8*)(Ps + tp * 64 + ca);
#pragma unroll
      for (int db = 0; db < 4; ++db) {
        const int vr = db * 16 + l15;
        const int cb = ((ks * 4 + kq) ^ (vr & 7)) << 3;
        O[db] = MFMA16(pa, *(const half8*)(VtS + vr * 64 + cb), O[db]);
      }
    }
    __builtin_amdgcn_s_setprio(0);
  }

  // ---- epilogue -> ao fp16 [B*T, 1024] ----
#pragma unroll
  for (int r = 0; r < 4; ++r) {
    const float inv = 1.f / ls[r];
    const int t = t0 + trow + r;
    h16* op = ao + ((size_t)(b * 1024 + t)) * 1024 + h * 64;
#pragma unroll
    for (int db = 0; db < 4; ++db) op[db * 16 + l15] = (h16)(O[db][r] * inv);
  }
}

// ---------- launch ----------
extern "C" void kernel_launch(void* const* d_in, const int* in_sizes, int n_in,
                              void* d_out, int out_size, void* d_ws,
                              size_t ws_size, hipStream_t stream) {
  const float* query = (const float*)d_in[0];
  const float* key = (const float*)d_in[1];
  const float* value = (const float*)d_in[2];
  const float* Wq = (const float*)d_in[3];
  const float* bq = (const float*)d_in[4];
  const float* Wk = (const float*)d_in[5];
  const float* bk = (const float*)d_in[6];
  const float* Wv = (const float*)d_in[7];
  const float* bv = (const float*)d_in[8];
  const float* Wo = (const float*)d_in[9];
  const float* bo = (const float*)d_in[10];
  const float* rel = (const float*)d_in[11];

  char* ws = (char*)d_ws;
  h16* q16c = (h16*)ws;                          // 8 MB raw query fp16
  h16* k16c = (h16*)(ws + ((size_t)8 << 20));    // 8 MB raw key (ao aliases)
  h16* v16c = (h16*)(ws + ((size_t)16 << 20));   // 8 MB raw value
  h16* Wq16 = (h16*)(ws + ((size_t)24 << 20));   // 2 MB
  h16* Wk16 = (h16*)(ws + ((size_t)26 << 20));   // 2 MB
  h16* Wv16 = (h16*)(ws + ((size_t)28 << 20));   // 2 MB
  h16* Wo16 = (h16*)(ws + ((size_t)30 << 20));   // 2 MB
  h16* q16 = (h16*)(ws + ((size_t)32 << 20));    // 8 MB [B,H,T,64]
  h16* k16 = (h16*)(ws + ((size_t)40 << 20));    // 8 MB [B,H,T,64]
  h16* vt16 = (h16*)(ws + ((size_t)48 << 20));   // 8 MB [B,H,64,T]
  h16* relb = (h16*)(ws + ((size_t)56 << 20));   // 0.25 MB [2000,64]
  h16* ao = k16c;  // k16c dead after qkv_gemm; attn writes ao here
  float* out = (float*)d_out;

  convert<<<16509, 256, 0, stream>>>(query, key, value, Wq, Wk, Wv, Wo, rel,
                                     q16c, k16c, v16c, Wq16, Wk16, Wv16, Wo16,
                                     relb);
  qkv_gemm<<<dim3(32, 8, 3), 256, 0, stream>>>(q16c, k16c, v16c, Wq16, Wk16,
                                               Wv16, bq, bk, bv, q16, k16,
                                               vt16);
  attn_mfma<<<1024, 256, 0, stream>>>(q16, k16, vt16, q16c, relb, ao);
  out_gemm<<<dim3(64, 8), 256, 0, stream>>>(ao, Wo16, bo, out);
}

// Round 14
// 251.961 us; speedup vs baseline: 1.2752x; 1.2752x over previous
//
#include <hip/hip_runtime.h>
#include <math.h>

typedef _Float16 h16;
typedef __attribute__((ext_vector_type(4))) _Float16 half4;
typedef __attribute__((ext_vector_type(8))) _Float16 half8;
typedef __attribute__((ext_vector_type(4))) float f32x4;

#define AS1 __attribute__((address_space(1)))
#define AS3 __attribute__((address_space(3)))
#define MFMA16(a, b, c) __builtin_amdgcn_mfma_f32_16x16x32_f16((a), (b), (c), 0, 0, 0)

__device__ __forceinline__ float ex2(float x) {
  return __builtin_amdgcn_exp2f(x);
}

// DPP lane ops (VALU pipe, not LDS pipe). Reduce within each 16-lane row.
template <int CTRL>
__device__ __forceinline__ float dppf(float x) {
  return __int_as_float(__builtin_amdgcn_update_dpp(
      0, __float_as_int(x), CTRL, 0xF, 0xF, true));
}
__device__ __forceinline__ float rmax16(float x) {
  x = fmaxf(x, dppf<0xB1>(x));   // quad_perm xor1
  x = fmaxf(x, dppf<0x4E>(x));   // quad_perm xor2
  x = fmaxf(x, dppf<0x124>(x));  // row_ror:4
  x = fmaxf(x, dppf<0x128>(x));  // row_ror:8
  return x;
}
__device__ __forceinline__ float rsum16(float x) {
  x += dppf<0xB1>(x);
  x += dppf<0x4E>(x);
  x += dppf<0x124>(x);
  x += dppf<0x128>(x);
  return x;
}

// ---------- convert: fp32 -> fp16 for q/k/v, Wq/Wk/Wv/Wo, rel ----------
__global__ __launch_bounds__(256) void convert(
    const float* __restrict__ q, const float* __restrict__ k,
    const float* __restrict__ v, const float* __restrict__ Wq,
    const float* __restrict__ Wk, const float* __restrict__ Wv,
    const float* __restrict__ Wo, const float* __restrict__ rel, h16* q16c,
    h16* k16c, h16* v16c, h16* Wq16, h16* Wk16, h16* Wv16, h16* Wo16,
    h16* relb) {
  const int i = blockIdx.x * 256 + threadIdx.x;  // float4 units
  if (i >= 4226304) return;
  const float* src;
  h16* dst;
  int off;
  if (i < 1048576) {
    src = q; dst = q16c; off = i;
  } else if (i < 2097152) {
    src = k; dst = k16c; off = i - 1048576;
  } else if (i < 3145728) {
    src = v; dst = v16c; off = i - 2097152;
  } else if (i < 3407872) {
    src = Wq; dst = Wq16; off = i - 3145728;
  } else if (i < 3670016) {
    src = Wk; dst = Wk16; off = i - 3407872;
  } else if (i < 3932160) {
    src = Wv; dst = Wv16; off = i - 3670016;
  } else if (i < 4194304) {
    src = Wo; dst = Wo16; off = i - 3932160;
  } else {
    off = i - 4194304;  // rel: 32000 f4 units; src valid below 31984
    half4 hv = (half4){(h16)0.f, (h16)0.f, (h16)0.f, (h16)0.f};
    if (off < 31984) {
      float4 f = *(const float4*)(rel + (size_t)off * 4);
      hv = (half4){(h16)f.x, (h16)f.y, (h16)f.z, (h16)f.w};
    }
    *(half4*)(relb + (size_t)off * 4) = hv;
    return;
  }
  float4 f = *(const float4*)(src + (size_t)off * 4);
  *(half4*)(dst + (size_t)off * 4) =
      (half4){(h16)f.x, (h16)f.y, (h16)f.z, (h16)f.w};
}

// ---------- 128x128 fp16 NT GEMM, BK=64, XOR-swizzled LDS ----------
// C[m,n] = sum_k A[m,k]*Bt[n,k] + bias[n]. M=4096,N=1024,K=1024.
// 2-phase; best-measured structure for this problem shape.
// MODE 0: h16 out scattered [B,H,T,64]; MODE 1: h16 out [B,H,64,T].
template <int MODE>
__device__ __forceinline__ void gemm128_body(const h16* __restrict__ A,
                                             const h16* __restrict__ Bt,
                                             const float* __restrict__ bias,
                                             h16* __restrict__ outp) {
  __shared__ alignas(16) h16 As[128 * 64];  // 16 KB swizzled
  __shared__ alignas(16) h16 Bs[128 * 64];  // 16 KB swizzled
  const int tid = threadIdx.x;
  const int wave = tid >> 6;
  const int lane = tid & 63;
  const int wm = wave >> 1, wn = wave & 1;
  const int tm0 = blockIdx.x * 128, tn0 = blockIdx.y * 128;
  const int lrow = lane & 15;
  const int kq = lane >> 4;

  f32x4 acc[4][4];
#pragma unroll
  for (int i = 0; i < 4; ++i)
#pragma unroll
    for (int j = 0; j < 4; ++j) acc[i][j] = (f32x4){0.f, 0.f, 0.f, 0.f};

  for (int k0 = 0; k0 < 1024; k0 += 64) {
    __syncthreads();
    // stage: each matrix = 1024 16B-units (128 rows x 8 units); 4/thread.
    // linear LDS dest unit a -> row = a>>3, cu = a&7, global col unit
    // c = cu ^ (row&7)  (inverse swizzle at the source)
#pragma unroll
    for (int p = 0; p < 4; ++p) {
      const int a = (wave * 4 + p) * 64 + lane;
      const int row = a >> 3;
      const int c = (a & 7) ^ (row & 7);
      __builtin_amdgcn_global_load_lds(
          (const AS1 void*)(A + (size_t)(tm0 + row) * 1024 + k0 + c * 8),
          (AS3 void*)(As + (wave * 4 + p) * 512), 16, 0, 0);
      __builtin_amdgcn_global_load_lds(
          (const AS1 void*)(Bt + (size_t)(tn0 + row) * 1024 + k0 + c * 8),
          (AS3 void*)(Bs + (wave * 4 + p) * 512), 16, 0, 0);
    }
    __syncthreads();
    // all fragment rows are (multiple of 16) + lrow -> row&7 == lrow&7
#pragma unroll
    for (int ks2 = 0; ks2 < 2; ++ks2) {
      const int cu = ((ks2 * 4 + kq) ^ (lrow & 7)) << 3;  // h16 offset
      half8 af[4], bf[4];
#pragma unroll
      for (int i = 0; i < 4; ++i)
        af[i] = *(const half8*)(As + (wm * 64 + i * 16 + lrow) * 64 + cu);
#pragma unroll
      for (int j = 0; j < 4; ++j)
        bf[j] = *(const half8*)(Bs + (wn * 64 + j * 16 + lrow) * 64 + cu);
#pragma unroll
      for (int i = 0; i < 4; ++i)
#pragma unroll
        for (int j = 0; j < 4; ++j)
          acc[i][j] = MFMA16(af[i], bf[j], acc[i][j]);
    }
  }

#pragma unroll
  for (int j = 0; j < 4; ++j) {
    const int n = tn0 + wn * 64 + j * 16 + lrow;
    const float bval = bias[n];
#pragma unroll
    for (int i = 0; i < 4; ++i) {
      const int rowb = wm * 64 + i * 16 + (lane >> 4) * 4;
#pragma unroll
      for (int r = 0; r < 4; ++r) {
        const int m = tm0 + rowb + r;
        const float val = acc[i][j][r] + bval;
        const int b = m >> 10, t = m & 1023, hh = n >> 6, d = n & 63;
        if (MODE == 0) {
          outp[((size_t)((b << 4) + hh) << 16) + (t << 6) + d] = (h16)val;
        } else {
          outp[(((size_t)((b << 4) + hh) * 64 + d) << 10) + t] = (h16)val;
        }
      }
    }
  }
}

__global__ __launch_bounds__(256) void qkv_gemm(
    const h16* q16c, const h16* k16c, const h16* v16c, const h16* Wq16,
    const h16* Wk16, const h16* Wv16, const float* bq, const float* bk,
    const float* bv, h16* q16, h16* k16, h16* vt16) {
  const int z = blockIdx.z;
  const h16* A = (z == 0) ? q16c : (z == 1) ? k16c : v16c;
  const h16* Bt = (z == 0) ? Wq16 : (z == 1) ? Wk16 : Wv16;
  const float* bias = (z == 0) ? bq : (z == 1) ? bk : bv;
  if (z == 2)
    gemm128_body<1>(A, Bt, bias, vt16);
  else
    gemm128_body<0>(A, Bt, bias, (z == 0) ? q16 : k16);
}

// ---------- out GEMM: 64x128 tile, BK=64, swizzled (512 blocks) ----------
__global__ __launch_bounds__(256) void out_gemm(const h16* __restrict__ A,
                                                const h16* __restrict__ Bt,
                                                const float* __restrict__ bo,
                                                float* __restrict__ out) {
  __shared__ alignas(16) h16 As[64 * 64];   // 8 KB swizzled
  __shared__ alignas(16) h16 Bs[128 * 64];  // 16 KB swizzled
  const int tid = threadIdx.x;
  const int wave = tid >> 6;
  const int lane = tid & 63;
  const int wm = wave >> 1, wn = wave & 1;
  const int tm0 = blockIdx.x * 64, tn0 = blockIdx.y * 128;
  const int lrow = lane & 15;
  const int kq = lane >> 4;

  f32x4 acc[2][4];
#pragma unroll
  for (int i = 0; i < 2; ++i)
#pragma unroll
    for (int j = 0; j < 4; ++j) acc[i][j] = (f32x4){0.f, 0.f, 0.f, 0.f};

  for (int k0 = 0; k0 < 1024; k0 += 64) {
    __syncthreads();
#pragma unroll
    for (int p = 0; p < 2; ++p) {  // A tile: 512 units, 2/thread
      const int a = (wave * 2 + p) * 64 + lane;
      const int row = a >> 3;  // 0..63
      const int c = (a & 7) ^ (row & 7);
      __builtin_amdgcn_global_load_lds(
          (const AS1 void*)(A + (size_t)(tm0 + row) * 1024 + k0 + c * 8),
          (AS3 void*)(As + (wave * 2 + p) * 512), 16, 0, 0);
    }
#pragma unroll
    for (int p = 0; p < 4; ++p) {  // B tile: 1024 units, 4/thread
      const int a = (wave * 4 + p) * 64 + lane;
      const int row = a >> 3;  // 0..127
      const int c = (a & 7) ^ (row & 7);
      __builtin_amdgcn_global_load_lds(
          (const AS1 void*)(Bt + (size_t)(tn0 + row) * 1024 + k0 + c * 8),
          (AS3 void*)(Bs + (wave * 4 + p) * 512), 16, 0, 0);
    }
    __syncthreads();
#pragma unroll
    for (int ks2 = 0; ks2 < 2; ++ks2) {
      const int cu = ((ks2 * 4 + kq) ^ (lrow & 7)) << 3;
      half8 af[2], bf[4];
#pragma unroll
      for (int i = 0; i < 2; ++i)
        af[i] = *(const half8*)(As + (wm * 32 + i * 16 + lrow) * 64 + cu);
#pragma unroll
      for (int j = 0; j < 4; ++j)
        bf[j] = *(const half8*)(Bs + (wn * 64 + j * 16 + lrow) * 64 + cu);
#pragma unroll
      for (int i = 0; i < 2; ++i)
#pragma unroll
        for (int j = 0; j < 4; ++j)
          acc[i][j] = MFMA16(af[i], bf[j], acc[i][j]);
    }
  }

#pragma unroll
  for (int j = 0; j < 4; ++j) {
    const int n = tn0 + wn * 64 + j * 16 + lrow;
    const float bval = bo[n];
#pragma unroll
    for (int i = 0; i < 2; ++i) {
      const int rowb = wm * 32 + i * 16 + kq * 4;
#pragma unroll
      for (int r = 0; r < 4; ++r) {
        const int m = tm0 + rowb + r;
        out[(size_t)m * 1024 + n] = acc[i][j][r] + bval;
      }
    }
  }
}

// ---------- MFMA fused attention (fp16) — R1/R9 config (best measured) ----------
// grid 1024 = (bh, ttile); 4 waves; wave w owns q rows t0+w*16..+15.
// All operands via global_load_lds (direct-to-VGPR operand loads lose:
// the compiler's vmcnt(0)-before-s_barrier drain serializes their latency
// regardless of use site — proven R2-R5). 40 KB LDS, 2 barriers/iter.
// NOTE: classic every-tile rescale softmax is load-bearing — T13 defer-max
// (R12/R13) tripled HBM FETCH via a timing/cache-reuse interaction. Do not
// re-apply without a mechanism model.
__global__ __launch_bounds__(256, 4) void attn_mfma(
    const h16* __restrict__ q16, const h16* __restrict__ k16,
    const h16* __restrict__ vt16, const h16* __restrict__ q16c,
    const h16* __restrict__ relb, h16* __restrict__ ao) {
  __shared__ alignas(16) h16 Kh[4096];   // 8 KB [64][64] swizzled
  __shared__ alignas(16) h16 Rl[8192];   // 16 KB [128][64] swizzled
  __shared__ alignas(16) h16 VtS[4096];  // 8 KB [64][64] swizzled
  __shared__ alignas(16) h16 Ps[4096];   // 8 KB [64][64] swizzled

  const int bid = blockIdx.x;
  const int ttile = bid & 15;
  const int bh = bid >> 4;
  const int b = bh >> 4, h = bh & 15;
  const int t0 = ttile << 6;
  const int tid = threadIdx.x;
  const int w = tid >> 6;
  const int lane = tid & 63;
  const int l15 = lane & 15;
  const int kq = lane >> 4;

  // Q fragment (projected) + raw-Q fragment, fp16, reused across s-tiles
  const int tq = t0 + w * 16 + l15;
  half8 aq[2], arq[2];
#pragma unroll
  for (int ks = 0; ks < 2; ++ks) {
    aq[ks] =
        *(const half8*)(q16 + ((size_t)bh * 1024 + tq) * 64 + kq * 8 + ks * 32);
    arq[ks] = *(const half8*)(q16c + ((size_t)(b * 1024 + tq)) * 1024 + h * 64 +
                              kq * 8 + ks * 32);
  }

  float m2[4], ls[4];
  f32x4 O[4];
#pragma unroll
  for (int r = 0; r < 4; ++r) {
    m2[r] = -1e30f;
    ls[r] = 0.f;
  }
#pragma unroll
  for (int db = 0; db < 4; ++db) O[db] = (f32x4){0.f, 0.f, 0.f, 0.f};

  const int trow = w * 16 + kq * 4;  // lane's block-local t base

  for (int s0 = 0; s0 < 1024; s0 += 64) {
    __syncthreads();  // all waves done reading Kh/Rl/VtS from prev iter

    // ---- staging: linear LDS dest, inverse-swizzled global source ----
    // unit a (16B) -> row = a>>3, cperm = a&7; source col c = cperm^(row&7)
#pragma unroll
    for (int p = 0; p < 2; ++p) {  // Kh: 8 KB = 8 wave-chunks, 2/wave
      const int a = (w * 2 + p) * 64 + lane;
      const int row = a >> 3;
      const int c = (a & 7) ^ (row & 7);
      __builtin_amdgcn_global_load_lds(
          (const AS1 void*)(k16 + ((size_t)(bh * 1024 + s0 + row)) * 64 +
                            c * 8),
          (AS3 void*)(Kh + (w * 2 + p) * 512), 16, 0, 0);
    }
#pragma unroll
    for (int p = 0; p < 2; ++p) {  // VtS: 8 KB, rows are d
      const int a = (w * 2 + p) * 64 + lane;
      const int row = a >> 3;
      const int c = (a & 7) ^ (row & 7);
      __builtin_amdgcn_global_load_lds(
          (const AS1 void*)(vt16 + ((size_t)(bh * 64 + row)) * 1024 + s0 +
                            c * 8),
          (AS3 void*)(VtS + (w * 2 + p) * 512), 16, 0, 0);
    }
    const int base = s0 - t0 + 999 - 63;
#pragma unroll
    for (int p = 0; p < 4; ++p) {  // Rl: 16 KB = 16 wave-chunks, 4/wave
      const int a = (w * 4 + p) * 64 + lane;
      const int row = a >> 3;
      const int c = (a & 7) ^ (row & 7);
      int ridx = base + row;
      ridx = ridx < 0 ? 0 : (ridx > 1998 ? 1998 : ridx);
      __builtin_amdgcn_global_load_lds(
          (const AS1 void*)(relb + (size_t)ridx * 64 + c * 8),
          (AS3 void*)(Rl + (w * 4 + p) * 512), 16, 0, 0);
    }
    __syncthreads();  // implicit vmcnt(0) drain -> LDS tiles ready

    // ---- QK^T strips ----
    __builtin_amdgcn_s_setprio(1);
    f32x4 S[4];
#pragma unroll
    for (int ns = 0; ns < 4; ++ns) {
      f32x4 s = (f32x4){0.f, 0.f, 0.f, 0.f};
      const int kr = ns * 16 + l15;
#pragma unroll
      for (int ks = 0; ks < 2; ++ks) {
        const int c = ((ks * 4 + kq) ^ (kr & 7)) << 3;
        s = MFMA16(aq[ks], *(const half8*)(Kh + kr * 64 + c), s);
      }
      S[ns] = s;
    }

    // ---- G[t][u] = rq . rel[u]; wave's u-window [(3-w)*16, (8-w)*16) ----
    f32x4 G[5];
#pragma unroll
    for (int gi = 0; gi < 5; ++gi) {
      f32x4 g = (f32x4){0.f, 0.f, 0.f, 0.f};
      const int ur = (3 - w + gi) * 16 + l15;
#pragma unroll
      for (int ks = 0; ks < 2; ++ks) {
        const int c = ((ks * 4 + kq) ^ (ur & 7)) << 3;
        g = MFMA16(arq[ks], *(const half8*)(Rl + ur * 64 + c), g);
      }
      G[gi] = g;
    }
    __builtin_amdgcn_s_setprio(0);

    // ---- in-register Toeplitz gather + logit scale ----
    // C = C0 + ns*16 - r = 16*(3+ns-w) + (15-kq*4-r); Cm = 15-kq*4-r is
    // ns-independent -> 1 bpermute per (ns,r) with merged select.
    const float SC = 11.54156032711170727f;  // 8 * log2(e)
#pragma unroll
    for (int r = 0; r < 4; ++r) {
      const int Cm = 15 - kq * 4 - r;
      const int sladdr = ((kq << 4) | ((l15 + Cm) & 15)) << 2;
      const bool nolap = (l15 >= Cm);
#pragma unroll
      for (int ns = 0; ns < 4; ++ns) {
        const float mv = nolap ? G[ns][r] : G[ns + 1][r];
        const float g = __int_as_float(
            __builtin_amdgcn_ds_bpermute(sladdr, __float_as_int(mv)));
        S[ns][r] = (S[ns][r] + g) * SC;
      }
    }

    // ---- online softmax (exp2 domain, DPP reduces) + P write ----
#pragma unroll
    for (int r = 0; r < 4; ++r) {
      float mx = fmaxf(fmaxf(S[0][r], S[1][r]), fmaxf(S[2][r], S[3][r]));
      mx = rmax16(mx);
      const float nm = fmaxf(m2[r], mx);
      const float al = ex2(m2[r] - nm);
      m2[r] = nm;
      const int t = trow + r;
      float rs = 0.f;
#pragma unroll
      for (int ns = 0; ns < 4; ++ns) {
        const float p = ex2(S[ns][r] - nm);
        rs += p;
        const int sl = ns * 16 + l15;
        Ps[t * 64 + (((sl >> 3) ^ (t & 7)) << 3) + (sl & 7)] = (h16)p;
      }
      rs = rsum16(rs);
      ls[r] = ls[r] * al + rs;
      O[0][r] *= al;
      O[1][r] *= al;
      O[2][r] *= al;
      O[3][r] *= al;
    }

    // ---- PV: O += P.V (A = own-wave P rows, B = VtS rows) ----
    const int tp = w * 16 + l15;
    __builtin_amdgcn_s_setprio(1);
#pragma unroll
    for (int ks = 0; ks < 2; ++ks) {
      const int ca = ((ks * 4 + kq) ^ (tp & 7)) << 3;
      half8 pa = *(const half8*)(Ps + tp * 64 + ca);
#pragma unroll
      for (int db = 0; db < 4; ++db) {
        const int vr = db * 16 + l15;
        const int cb = ((ks * 4 + kq) ^ (vr & 7)) << 3;
        O[db] = MFMA16(pa, *(const half8*)(VtS + vr * 64 + cb), O[db]);
      }
    }
    __builtin_amdgcn_s_setprio(0);
  }

  // ---- epilogue -> ao fp16 [B*T, 1024] ----
#pragma unroll
  for (int r = 0; r < 4; ++r) {
    const float inv = 1.f / ls[r];
    const int t = t0 + trow + r;
    h16* op = ao + ((size_t)(b * 1024 + t)) * 1024 + h * 64;
#pragma unroll
    for (int db = 0; db < 4; ++db) op[db * 16 + l15] = (h16)(O[db][r] * inv);
  }
}

// ---------- launch ----------
extern "C" void kernel_launch(void* const* d_in, const int* in_sizes, int n_in,
                              void* d_out, int out_size, void* d_ws,
                              size_t ws_size, hipStream_t stream) {
  const float* query = (const float*)d_in[0];
  const float* key = (const float*)d_in[1];
  const float* value = (const float*)d_in[2];
  const float* Wq = (const float*)d_in[3];
  const float* bq = (const float*)d_in[4];
  const float* Wk = (const float*)d_in[5];
  const float* bk = (const float*)d_in[6];
  const float* Wv = (const float*)d_in[7];
  const float* bv = (const float*)d_in[8];
  const float* Wo = (const float*)d_in[9];
  const float* bo = (const float*)d_in[10];
  const float* rel = (const float*)d_in[11];

  char* ws = (char*)d_ws;
  h16* q16c = (h16*)ws;                          // 8 MB raw query fp16
  h16* k16c = (h16*)(ws + ((size_t)8 << 20));    // 8 MB raw key (ao aliases)
  h16* v16c = (h16*)(ws + ((size_t)16 << 20));   // 8 MB raw value
  h16* Wq16 = (h16*)(ws + ((size_t)24 << 20));   // 2 MB
  h16* Wk16 = (h16*)(ws + ((size_t)26 << 20));   // 2 MB
  h16* Wv16 = (h16*)(ws + ((size_t)28 << 20));   // 2 MB
  h16* Wo16 = (h16*)(ws + ((size_t)30 << 20));   // 2 MB
  h16* q16 = (h16*)(ws + ((size_t)32 << 20));    // 8 MB [B,H,T,64]
  h16* k16 = (h16*)(ws + ((size_t)40 << 20));    // 8 MB [B,H,T,64]
  h16* vt16 = (h16*)(ws + ((size_t)48 << 20));   // 8 MB [B,H,64,T]
  h16* relb = (h16*)(ws + ((size_t)56 << 20));   // 0.25 MB [2000,64]
  h16* ao = k16c;  // k16c dead after qkv_gemm; attn writes ao here
  float* out = (float*)d_out;

  convert<<<16509, 256, 0, stream>>>(query, key, value, Wq, Wk, Wv, Wo, rel,
                                     q16c, k16c, v16c, Wq16, Wk16, Wv16, Wo16,
                                     relb);
  qkv_gemm<<<dim3(32, 8, 3), 256, 0, stream>>>(q16c, k16c, v16c, Wq16, Wk16,
                                               Wv16, bq, bk, bv, q16, k16,
                                               vt16);
  attn_mfma<<<1024, 256, 0, stream>>>(q16, k16, vt16, q16c, relb, ao);
  out_gemm<<<dim3(64, 8), 256, 0, stream>>>(ao, Wo16, bo, out);
}